// Round 3
// baseline (661.714 us; speedup 1.0000x reference)
//
#include <hip/hip_runtime.h>
#include <hip/hip_bf16.h>
#include <math.h>

#define B 8
#define N 10000
#define D 16
#define E 320000
#define EH 32
#define EOUT 30
#define NOUT 64
#define FEAT 35   // 2*D + 2 + 1

__device__ __forceinline__ float sigmoidf_(float v) {
    return 1.0f / (1.0f + __expf(-v));
}

__device__ __forceinline__ unsigned int pack_bf16_2(float a, float b) {
    unsigned ua = __float_as_uint(a), ub = __float_as_uint(b);
    ua = (ua + 0x7FFFu + ((ua >> 16) & 1u)) >> 16;
    ub = (ub + 0x7FFFu + ((ub >> 16) & 1u)) >> 16;
    return ua | (ub << 16);
}

// ---------------------------------------------------------------------------
// edge_attr column stats (mean / std ddof=1)
// ---------------------------------------------------------------------------
__global__ void stats_kernel(const float* __restrict__ ea, float* __restrict__ stats) {
    float s0 = 0.f, s1 = 0.f, q0 = 0.f, q1 = 0.f;
    for (int i = blockIdx.x * blockDim.x + threadIdx.x; i < E; i += gridDim.x * blockDim.x) {
        float2 v = *(const float2*)(ea + 2 * (size_t)i);
        s0 += v.x; q0 += v.x * v.x;
        s1 += v.y; q1 += v.y * v.y;
    }
    #pragma unroll
    for (int off = 32; off > 0; off >>= 1) {
        s0 += __shfl_down(s0, off);
        s1 += __shfl_down(s1, off);
        q0 += __shfl_down(q0, off);
        q1 += __shfl_down(q1, off);
    }
    if ((threadIdx.x & 63) == 0) {
        atomicAdd(&stats[0], s0);
        atomicAdd(&stats[1], s1);
        atomicAdd(&stats[2], q0);
        atomicAdd(&stats[3], q1);
    }
}

__global__ void finalize_kernel(float* __restrict__ stats) {
    if (threadIdx.x == 0 && blockIdx.x == 0) {
        const float n = (float)E;
        float s0 = stats[0], s1 = stats[1], q0 = stats[2], q1 = stats[3];
        float v0 = (q0 - s0 * s0 / n) / (n - 1.0f);
        float v1 = (q1 - s1 * s1 / n) / (n - 1.0f);
        stats[4] = s0 / n;
        stats[5] = 1.0f / sqrtf(v0);
        stats[6] = s1 / n;
        stats[7] = 1.0f / sqrtf(v1);
    }
}

// ---------------------------------------------------------------------------
// CSR binning: count -> scan -> fill (fill records each edge's 2 row slots)
// rows [0,E): in-lists (add), rows [E,2E): out-lists (subtract)
// ---------------------------------------------------------------------------
__global__ void count_kernel(const int* __restrict__ eidx, int* __restrict__ cnt) {
    int e = blockIdx.x * blockDim.x + threadIdx.x;
    if (e >= E) return;
    atomicAdd(&cnt[eidx[E + e]], 1);       // tgt
    atomicAdd(&cnt[N + eidx[e]], 1);       // src
}

__global__ void __launch_bounds__(1024) scan_kernel(const int* __restrict__ cnt_in,
                                                    int* __restrict__ offs,
                                                    int* __restrict__ cursor) {
    const int M = 2 * N;
    const int CH = 20;
    __shared__ int lds[1024];
    int t = threadIdx.x;
    int base = t * CH;
    int loc[CH];
    int s = 0;
    #pragma unroll
    for (int i = 0; i < CH; i++) {
        int idx = base + i;
        int v = (idx < M) ? cnt_in[idx] : 0;
        loc[i] = s;
        s += v;
    }
    lds[t] = s;
    __syncthreads();
    for (int off = 1; off < 1024; off <<= 1) {
        int v = (t >= off) ? lds[t - off] : 0;
        __syncthreads();
        lds[t] += v;
        __syncthreads();
    }
    int tbase = (t > 0) ? lds[t - 1] : 0;
    #pragma unroll
    for (int i = 0; i < CH; i++) {
        int idx = base + i;
        if (idx < M) {
            offs[idx] = tbase + loc[i];
            cursor[idx] = tbase + loc[i];
        }
    }
    if (t == 1023) offs[M] = lds[1023];
}

__global__ void fill_kernel(const int* __restrict__ eidx, int* __restrict__ cursor,
                            int* __restrict__ posT, int* __restrict__ posS) {
    int e = blockIdx.x * blockDim.x + threadIdx.x;
    if (e >= E) return;
    posT[e] = atomicAdd(&cursor[eidx[E + e]], 1);
    posS[e] = atomicAdd(&cursor[N + eidx[e]], 1);
}

// ---------------------------------------------------------------------------
// P/Q precompute: P[b,n,:] = x[b,n]@W1[0:16,:], Q[b,n,:] = x[b,n]@W1[16:32,:]+b1
// one wave per (b,n): lanes 0-31 -> P cols, lanes 32-63 -> Q cols
// ---------------------------------------------------------------------------
__global__ void __launch_bounds__(256) pq_kernel(
    const float* __restrict__ x, const float* __restrict__ W1,
    const float* __restrict__ b1, float* __restrict__ P, float* __restrict__ Q)
{
    int wid = (blockIdx.x * blockDim.x + threadIdx.x) >> 6;
    int lane = threadIdx.x & 63;
    if (wid >= B * N) return;
    int j = lane & 31;
    int half = lane >> 5;
    const float* xr = x + (size_t)wid * D;
    float acc = half ? b1[j] : 0.f;
    const float* Wb = W1 + (half ? D * EH : 0);
    #pragma unroll
    for (int d = 0; d < D; d++)
        acc = fmaf(xr[d], Wb[d * EH + j], acc);
    float* dst = half ? Q : P;
    dst[(size_t)wid * EH + j] = acc;
}

// ---------------------------------------------------------------------------
// Edge MLP with factored layer 1; stores bf16 e-row (64B) at both CSR slots
// ---------------------------------------------------------------------------
__global__ void __launch_bounds__(256) edge_mlp_kernel(
    const float* __restrict__ x, const int* __restrict__ eidx,
    const float* __restrict__ ea,
    const float* __restrict__ wind_mean, const float* __restrict__ wind_std,
    const float* __restrict__ W1, const float* __restrict__ W2,
    const float* __restrict__ b2, const float* __restrict__ stats,
    const float* __restrict__ P, const float* __restrict__ Q,
    const int* __restrict__ posT, const int* __restrict__ posS,
    unsigned short* __restrict__ eBuf, int b0, int nb)
{
    int t = blockIdx.x * blockDim.x + threadIdx.x;
    if (t >= nb * E) return;
    int bb = t / E;
    int e = t - bb * E;
    int b = b0 + bb;

    int src = eidx[e];
    int tgt = eidx[E + e];

    const float4* Pr = (const float4*)(P + ((size_t)b * N + src) * EH);
    const float4* Qr = (const float4*)(Q + ((size_t)b * N + tgt) * EH);

    float h[EH];
    #pragma unroll
    for (int i = 0; i < 8; i++) {
        float4 p = Pr[i];
        float4 q = Qr[i];
        h[4 * i + 0] = p.x + q.x;
        h[4 * i + 1] = p.y + q.y;
        h[4 * i + 2] = p.z + q.z;
        h[4 * i + 3] = p.w + q.w;
    }

    float2 eav = *(const float2*)(ea + 2 * (size_t)e);
    float dist = eav.x, cdir = eav.y;
    float f32v = (dist - stats[4]) * stats[5];
    float f33v = (cdir - stats[6]) * stats[7];

    float2 xw = *(const float2*)(x + ((size_t)b * N + src) * D + 14);
    float speed = xw.x * wind_std[0] + wind_mean[0];
    float sdir  = xw.y * wind_std[1] + wind_mean[1];
    float ew = fmaxf(3.0f * speed * cosf(fabsf(cdir - sdir)) / dist, 0.0f);

    const float* W1r32 = W1 + 32 * EH;
    const float* W1r33 = W1 + 33 * EH;
    const float* W1r34 = W1 + 34 * EH;
    #pragma unroll
    for (int j = 0; j < EH; j++) {
        float v = h[j];
        v = fmaf(f32v, W1r32[j], v);
        v = fmaf(f33v, W1r33[j], v);
        v = fmaf(ew,   W1r34[j], v);
        h[j] = sigmoidf_(v);
    }

    float o[EOUT];
    #pragma unroll
    for (int j = 0; j < EOUT; j++) o[j] = b2[j];
    #pragma unroll
    for (int k = 0; k < EH; k++) {
        float hk = h[k];
        #pragma unroll
        for (int j = 0; j < EOUT; j++)
            o[j] = fmaf(hk, W2[k * EOUT + j], o[j]);
    }

    uint4 u[4];
    unsigned* uu = (unsigned*)u;
    #pragma unroll
    for (int i = 0; i < 15; i++) {
        float a = sigmoidf_(o[2 * i]);
        float c = sigmoidf_(o[2 * i + 1]);
        uu[i] = pack_bf16_2(a, c);
    }
    uu[15] = 0u;

    size_t ebase = (size_t)bb * 2 * E * EH;
    uint4* rowT = (uint4*)(eBuf + ebase + (size_t)posT[e] * EH);
    uint4* rowS = (uint4*)(eBuf + ebase + (size_t)posS[e] * EH);
    #pragma unroll
    for (int i = 0; i < 4; i++) { rowT[i] = u[i]; rowS[i] = u[i]; }
}

// ---------------------------------------------------------------------------
// Gather (streaming, coalesced) + node MLP. One wave per (bb,node).
// Lanes 0-31 read row r, lanes 32-63 row r+1 (128B contiguous per iter).
// ---------------------------------------------------------------------------
__global__ void __launch_bounds__(256) gather_kernel(
    const unsigned short* __restrict__ eBuf, const int* __restrict__ offs,
    const float* __restrict__ Wn, const float* __restrict__ bn,
    float* __restrict__ out, int b0, int nb)
{
    int wid = (blockIdx.x * blockDim.x + threadIdx.x) >> 6;
    int lane = threadIdx.x & 63;
    if (wid >= nb * N) return;
    int bb = wid / N;
    int node = wid - bb * N;
    int b = b0 + bb;

    int half = lane >> 5;
    int col = lane & 31;
    const unsigned short* ebase = eBuf + (size_t)bb * 2 * E * EH;

    float acc = 0.f;
    {
        int s = offs[node], e1 = offs[node + 1];
        for (int r = s; r < e1; r += 2) {
            int row = r + half;
            if (row < e1) {
                unsigned short uv = ebase[(size_t)row * EH + col];
                acc += __uint_as_float(((unsigned)uv) << 16);
            }
        }
    }
    {
        int s = offs[N + node], e1 = offs[N + node + 1];
        for (int r = s; r < e1; r += 2) {
            int row = r + half;
            if (row < e1) {
                unsigned short uv = ebase[(size_t)row * EH + col];
                acc -= __uint_as_float(((unsigned)uv) << 16);
            }
        }
    }

    float tot = acc + __shfl(acc, lane ^ 32);   // lane holds agg[col]

    float o = bn[lane];
    #pragma unroll
    for (int k = 0; k < EOUT; k++) {
        float ak = __shfl(tot, k);
        o = fmaf(ak, Wn[k * NOUT + lane], o);
    }
    out[((size_t)b * N + node) * NOUT + lane] = sigmoidf_(o);
}

// ---------------------------------------------------------------------------
// Fallback (small ws): atomic path
// ---------------------------------------------------------------------------
__global__ void __launch_bounds__(256) edge_kernel_atomic(
    const float* __restrict__ x, const int* __restrict__ eidx,
    const float* __restrict__ ea,
    const float* __restrict__ wind_mean, const float* __restrict__ wind_std,
    const float* __restrict__ W1, const float* __restrict__ b1,
    const float* __restrict__ W2, const float* __restrict__ b2,
    const float* __restrict__ stats, float* __restrict__ agg)
{
    int t = blockIdx.x * blockDim.x + threadIdx.x;
    if (t >= B * E) return;
    int b = t / E;
    int e = t - b * E;
    int src = eidx[e];
    int tgt = eidx[E + e];
    const float* xs = x + ((size_t)b * N + src) * D;
    const float* xt = x + ((size_t)b * N + tgt) * D;
    float f[FEAT];
    #pragma unroll
    for (int i = 0; i < D; i++) f[i] = xs[i];
    #pragma unroll
    for (int i = 0; i < D; i++) f[D + i] = xt[i];
    float2 eav = *(const float2*)(ea + 2 * (size_t)e);
    f[32] = (eav.x - stats[4]) * stats[5];
    f[33] = (eav.y - stats[6]) * stats[7];
    float speed = f[14] * wind_std[0] + wind_mean[0];
    float sdir  = f[15] * wind_std[1] + wind_mean[1];
    f[34] = fmaxf(3.0f * speed * cosf(fabsf(eav.y - sdir)) / eav.x, 0.0f);
    float h[EH];
    #pragma unroll
    for (int j = 0; j < EH; j++) h[j] = b1[j];
    #pragma unroll
    for (int k = 0; k < FEAT; k++) {
        float fk = f[k];
        #pragma unroll
        for (int j = 0; j < EH; j++) h[j] = fmaf(fk, W1[k * EH + j], h[j]);
    }
    #pragma unroll
    for (int j = 0; j < EH; j++) h[j] = sigmoidf_(h[j]);
    float o[EOUT];
    #pragma unroll
    for (int j = 0; j < EOUT; j++) o[j] = b2[j];
    #pragma unroll
    for (int k = 0; k < EH; k++) {
        float hk = h[k];
        #pragma unroll
        for (int j = 0; j < EOUT; j++) o[j] = fmaf(hk, W2[k * EOUT + j], o[j]);
    }
    float* at = agg + ((size_t)b * N + tgt) * EOUT;
    float* as = agg + ((size_t)b * N + src) * EOUT;
    #pragma unroll
    for (int j = 0; j < EOUT; j++) {
        float v = sigmoidf_(o[j]);
        atomicAdd(at + j,  v);
        atomicAdd(as + j, -v);
    }
}

__global__ void __launch_bounds__(256) node_kernel_fallback(
    const float* __restrict__ agg, const float* __restrict__ Wn,
    const float* __restrict__ bn, float* __restrict__ out)
{
    int t = blockIdx.x * blockDim.x + threadIdx.x;
    if (t >= B * N * NOUT) return;
    int row = t >> 6;
    int j   = t & 63;
    const float* a = agg + (size_t)row * EOUT;
    float acc = bn[j];
    #pragma unroll
    for (int k = 0; k < EOUT; k++) acc = fmaf(a[k], Wn[k * NOUT + j], acc);
    out[t] = sigmoidf_(acc);
}

// ---------------------------------------------------------------------------
extern "C" void kernel_launch(void* const* d_in, const int* in_sizes, int n_in,
                              void* d_out, int out_size, void* d_ws, size_t ws_size,
                              hipStream_t stream) {
    const float* x         = (const float*)d_in[0];
    const int*   eidx      = (const int*)d_in[1];
    const float* ea        = (const float*)d_in[2];
    const float* wind_mean = (const float*)d_in[3];
    const float* wind_std  = (const float*)d_in[4];
    const float* W1        = (const float*)d_in[5];
    const float* b1        = (const float*)d_in[6];
    const float* W2        = (const float*)d_in[7];
    const float* b2        = (const float*)d_in[8];
    const float* Wn        = (const float*)d_in[9];
    const float* bn        = (const float*)d_in[10];
    float* out = (float*)d_out;

    char* ws = (char*)d_ws;
    // layout:
    //   stats [0,256) | offs [256,80384) | cnt/cursor [80384,160512)
    //   posT [160512,1440512) | posS [1440512,2720512)
    //   P [2720512,12960512) | Q [12960512,23200512) | eBuf [23200512,...)
    float*          stats = (float*)(ws + 0);
    int*            offs  = (int*)(ws + 256);
    int*            cnt   = (int*)(ws + 80384);
    int*            posT  = (int*)(ws + 160512);
    int*            posS  = (int*)(ws + 1440512);
    float*          P     = (float*)(ws + 2720512);
    float*          Q     = (float*)(ws + 12960512);
    unsigned short* eBuf  = (unsigned short*)(ws + 23200512);
    const size_t fixed = 23200512;
    const size_t perBatch = (size_t)2 * E * EH * sizeof(unsigned short); // 40,960,000

    if (ws_size >= fixed + perBatch) {
        int chunk = (int)((ws_size - fixed) / perBatch);
        if (chunk > 2) chunk = 2;   // keep eBuf chunk L3-resident (82 MB)

        hipMemsetAsync(ws, 0, 160512, stream);

        stats_kernel<<<256, 256, 0, stream>>>(ea, stats);
        finalize_kernel<<<1, 64, 0, stream>>>(stats);
        count_kernel<<<(E + 255) / 256, 256, 0, stream>>>(eidx, cnt);
        scan_kernel<<<1, 1024, 0, stream>>>(cnt, offs, cnt);
        fill_kernel<<<(E + 255) / 256, 256, 0, stream>>>(eidx, cnt, posT, posS);
        pq_kernel<<<(B * N * 64) / 256, 256, 0, stream>>>(x, W1, b1, P, Q);

        for (int b0 = 0; b0 < B; b0 += chunk) {
            int nb = B - b0; if (nb > chunk) nb = chunk;
            int nwork = nb * E;
            edge_mlp_kernel<<<(nwork + 255) / 256, 256, 0, stream>>>(
                x, eidx, ea, wind_mean, wind_std, W1, W2, b2, stats,
                P, Q, posT, posS, eBuf, b0, nb);
            gather_kernel<<<nb * (N * 64 / 256), 256, 0, stream>>>(
                eBuf, offs, Wn, bn, out, b0, nb);
        }
    } else {
        float* agg = (float*)(ws + 256);
        size_t zero_bytes = 256 + (size_t)B * N * EOUT * sizeof(float);
        hipMemsetAsync(ws, 0, zero_bytes, stream);
        stats_kernel<<<256, 256, 0, stream>>>(ea, stats);
        finalize_kernel<<<1, 64, 0, stream>>>(stats);
        int nwork = B * E;
        edge_kernel_atomic<<<(nwork + 255) / 256, 256, 0, stream>>>(
            x, eidx, ea, wind_mean, wind_std, W1, b1, W2, b2, stats, agg);
        int nout_elems = B * N * NOUT;
        node_kernel_fallback<<<(nout_elems + 255) / 256, 256, 0, stream>>>(
            agg, Wn, bn, out);
    }
}

// Round 4
// 530.705 us; speedup vs baseline: 1.2469x; 1.2469x over previous
//
#include <hip/hip_runtime.h>
#include <hip/hip_bf16.h>
#include <math.h>

#define B 8
#define N 10000
#define D 16
#define E 320000
#define EH 32
#define EOUT 30
#define NOUT 64
#define FEAT 35   // 2*D + 2 + 1

__device__ __forceinline__ float sigmoidf_(float v) {
    return 1.0f / (1.0f + __expf(-v));
}

__device__ __forceinline__ unsigned int pack_bf16_2(float a, float b) {
    unsigned ua = __float_as_uint(a), ub = __float_as_uint(b);
    ua = (ua + 0x7FFFu + ((ua >> 16) & 1u)) >> 16;
    ub = (ub + 0x7FFFu + ((ub >> 16) & 1u)) >> 16;
    return ua | (ub << 16);
}

// ---------------------------------------------------------------------------
// edge_attr column stats (mean / std ddof=1)
// ---------------------------------------------------------------------------
__global__ void stats_kernel(const float* __restrict__ ea, float* __restrict__ stats) {
    float s0 = 0.f, s1 = 0.f, q0 = 0.f, q1 = 0.f;
    for (int i = blockIdx.x * blockDim.x + threadIdx.x; i < E; i += gridDim.x * blockDim.x) {
        float2 v = *(const float2*)(ea + 2 * (size_t)i);
        s0 += v.x; q0 += v.x * v.x;
        s1 += v.y; q1 += v.y * v.y;
    }
    #pragma unroll
    for (int off = 32; off > 0; off >>= 1) {
        s0 += __shfl_down(s0, off);
        s1 += __shfl_down(s1, off);
        q0 += __shfl_down(q0, off);
        q1 += __shfl_down(q1, off);
    }
    if ((threadIdx.x & 63) == 0) {
        atomicAdd(&stats[0], s0);
        atomicAdd(&stats[1], s1);
        atomicAdd(&stats[2], q0);
        atomicAdd(&stats[3], q1);
    }
}

__global__ void finalize_kernel(float* __restrict__ stats) {
    if (threadIdx.x == 0 && blockIdx.x == 0) {
        const float n = (float)E;
        float s0 = stats[0], s1 = stats[1], q0 = stats[2], q1 = stats[3];
        float v0 = (q0 - s0 * s0 / n) / (n - 1.0f);
        float v1 = (q1 - s1 * s1 / n) / (n - 1.0f);
        stats[4] = s0 / n;
        stats[5] = 1.0f / sqrtf(v0);
        stats[6] = s1 / n;
        stats[7] = 1.0f / sqrtf(v1);
    }
}

// ---------------------------------------------------------------------------
// CSR binning: count -> scan -> fill. in-segments occupy [0,E), out [E,2E).
// ---------------------------------------------------------------------------
__global__ void count_kernel(const int* __restrict__ eidx, int* __restrict__ cnt) {
    int e = blockIdx.x * blockDim.x + threadIdx.x;
    if (e >= E) return;
    atomicAdd(&cnt[eidx[E + e]], 1);       // tgt (in)
    atomicAdd(&cnt[N + eidx[e]], 1);       // src (out)
}

__global__ void __launch_bounds__(1024) scan_kernel(const int* __restrict__ cnt_in,
                                                    int* __restrict__ offs,
                                                    int* __restrict__ cursor) {
    const int M = 2 * N;
    const int CH = 20;
    __shared__ int lds[1024];
    int t = threadIdx.x;
    int base = t * CH;
    int loc[CH];
    int s = 0;
    #pragma unroll
    for (int i = 0; i < CH; i++) {
        int idx = base + i;
        int v = (idx < M) ? cnt_in[idx] : 0;
        loc[i] = s;
        s += v;
    }
    lds[t] = s;
    __syncthreads();
    for (int off = 1; off < 1024; off <<= 1) {
        int v = (t >= off) ? lds[t - off] : 0;
        __syncthreads();
        lds[t] += v;
        __syncthreads();
    }
    int tbase = (t > 0) ? lds[t - 1] : 0;
    #pragma unroll
    for (int i = 0; i < CH; i++) {
        int idx = base + i;
        if (idx < M) {
            offs[idx] = tbase + loc[i];
            cursor[idx] = tbase + loc[i];
        }
    }
    if (t == 1023) offs[M] = lds[1023];
}

__global__ void fill_kernel(const int* __restrict__ eidx, int* __restrict__ cursor,
                            int* __restrict__ lists) {
    int e = blockIdx.x * blockDim.x + threadIdx.x;
    if (e >= E) return;
    int p = atomicAdd(&cursor[eidx[E + e]], 1);
    lists[p] = e;
    int q = atomicAdd(&cursor[N + eidx[e]], 1);
    lists[q] = e;
}

// ---------------------------------------------------------------------------
// P/Q precompute: P[b,n,:] = x[b,n]@W1[0:16,:], Q[b,n,:] = x[b,n]@W1[16:32,:]+b1
// ---------------------------------------------------------------------------
__global__ void __launch_bounds__(256) pq_kernel(
    const float* __restrict__ x, const float* __restrict__ W1,
    const float* __restrict__ b1, float* __restrict__ P, float* __restrict__ Q)
{
    int wid = (blockIdx.x * blockDim.x + threadIdx.x) >> 6;
    int lane = threadIdx.x & 63;
    if (wid >= B * N) return;
    int j = lane & 31;
    int half = lane >> 5;
    const float* xr = x + (size_t)wid * D;
    float acc = half ? b1[j] : 0.f;
    const float* Wb = W1 + (half ? D * EH : 0);
    #pragma unroll
    for (int d = 0; d < D; d++)
        acc = fmaf(xr[d], Wb[d * EH + j], acc);
    float* dst = half ? Q : P;
    dst[(size_t)wid * EH + j] = acc;
}

// ---------------------------------------------------------------------------
// Edge MLP (factored layer 1); stores ONE bf16 row (64B) per edge, edge order
// ---------------------------------------------------------------------------
__global__ void __launch_bounds__(256) edge_mlp_kernel(
    const float* __restrict__ x, const int* __restrict__ eidx,
    const float* __restrict__ ea,
    const float* __restrict__ wind_mean, const float* __restrict__ wind_std,
    const float* __restrict__ W1, const float* __restrict__ W2,
    const float* __restrict__ b2, const float* __restrict__ stats,
    const float* __restrict__ P, const float* __restrict__ Q,
    unsigned short* __restrict__ eBuf, int b0, int nb)
{
    int t = blockIdx.x * blockDim.x + threadIdx.x;
    if (t >= nb * E) return;
    int bb = t / E;
    int e = t - bb * E;
    int b = b0 + bb;

    int src = eidx[e];
    int tgt = eidx[E + e];

    const float4* Pr = (const float4*)(P + ((size_t)b * N + src) * EH);
    const float4* Qr = (const float4*)(Q + ((size_t)b * N + tgt) * EH);

    float h[EH];
    #pragma unroll
    for (int i = 0; i < 8; i++) {
        float4 p = Pr[i];
        float4 q = Qr[i];
        h[4 * i + 0] = p.x + q.x;
        h[4 * i + 1] = p.y + q.y;
        h[4 * i + 2] = p.z + q.z;
        h[4 * i + 3] = p.w + q.w;
    }

    float2 eav = *(const float2*)(ea + 2 * (size_t)e);
    float dist = eav.x, cdir = eav.y;
    float f32v = (dist - stats[4]) * stats[5];
    float f33v = (cdir - stats[6]) * stats[7];

    float2 xw = *(const float2*)(x + ((size_t)b * N + src) * D + 14);
    float speed = xw.x * wind_std[0] + wind_mean[0];
    float sdir  = xw.y * wind_std[1] + wind_mean[1];
    float ew = fmaxf(3.0f * speed * cosf(fabsf(cdir - sdir)) / dist, 0.0f);

    const float* W1r32 = W1 + 32 * EH;
    const float* W1r33 = W1 + 33 * EH;
    const float* W1r34 = W1 + 34 * EH;
    #pragma unroll
    for (int j = 0; j < EH; j++) {
        float v = h[j];
        v = fmaf(f32v, W1r32[j], v);
        v = fmaf(f33v, W1r33[j], v);
        v = fmaf(ew,   W1r34[j], v);
        h[j] = sigmoidf_(v);
    }

    float o[EOUT];
    #pragma unroll
    for (int j = 0; j < EOUT; j++) o[j] = b2[j];
    #pragma unroll
    for (int k = 0; k < EH; k++) {
        float hk = h[k];
        #pragma unroll
        for (int j = 0; j < EOUT; j++)
            o[j] = fmaf(hk, W2[k * EOUT + j], o[j]);
    }

    uint4 u[4];
    unsigned* uu = (unsigned*)u;
    #pragma unroll
    for (int i = 0; i < 15; i++) {
        float a = sigmoidf_(o[2 * i]);
        float c = sigmoidf_(o[2 * i + 1]);
        uu[i] = pack_bf16_2(a, c);
    }
    uu[15] = 0u;

    uint4* row = (uint4*)(eBuf + ((size_t)bb * E + e) * EH);
    #pragma unroll
    for (int i = 0; i < 4; i++) row[i] = u[i];
}

// ---------------------------------------------------------------------------
// Gather + node MLP. One wave per (bb,node). Packed: each lane loads a uint
// (2 bf16 cols); 16 lanes/row -> 4 rows per wave iteration (256 B/instr).
// Quarter-fold via shfl_xor, then 30->64 node layer.
// ---------------------------------------------------------------------------
__global__ void __launch_bounds__(256) gather_kernel(
    const unsigned short* __restrict__ eBuf, const int* __restrict__ offs,
    const int* __restrict__ lists, const float* __restrict__ Wn,
    const float* __restrict__ bn, float* __restrict__ out, int b0, int nb)
{
    int wid = (blockIdx.x * blockDim.x + threadIdx.x) >> 6;
    int lane = threadIdx.x & 63;
    if (wid >= nb * N) return;
    int bb = wid / N;
    int node = wid - bb * N;
    int b = b0 + bb;

    int q  = lane >> 4;      // quarter 0..3 -> which row of the group of 4
    int c2 = lane & 15;      // uint index: covers cols 2*c2, 2*c2+1
    const unsigned* ebase = (const unsigned*)(eBuf + (size_t)bb * E * EH); // row stride 16 uints

    float acc0 = 0.f, acc1 = 0.f;

    // in-list: add
    {
        int s = offs[node], e1 = offs[node + 1];
        for (int base = s; base < e1; base += 64) {
            int n = e1 - base; if (n > 64) n = 64;
            int myeid = (lane < n) ? lists[base + lane] : 0;
            for (int i = 0; i < n; i += 4) {
                int sel = i + q;
                int eid = __shfl(myeid, sel);
                if (sel < n) {
                    unsigned v = ebase[(size_t)eid * 16 + c2];
                    acc0 += __uint_as_float(v << 16);
                    acc1 += __uint_as_float(v & 0xFFFF0000u);
                }
            }
        }
    }
    // out-list: subtract
    {
        int s = offs[N + node], e1 = offs[N + node + 1];
        for (int base = s; base < e1; base += 64) {
            int n = e1 - base; if (n > 64) n = 64;
            int myeid = (lane < n) ? lists[base + lane] : 0;
            for (int i = 0; i < n; i += 4) {
                int sel = i + q;
                int eid = __shfl(myeid, sel);
                if (sel < n) {
                    unsigned v = ebase[(size_t)eid * 16 + c2];
                    acc0 -= __uint_as_float(v << 16);
                    acc1 -= __uint_as_float(v & 0xFFFF0000u);
                }
            }
        }
    }

    // fold quarters: all lanes with same (lane&15) end up with full column sums
    acc0 += __shfl_xor(acc0, 16); acc1 += __shfl_xor(acc1, 16);
    acc0 += __shfl_xor(acc0, 32); acc1 += __shfl_xor(acc1, 32);

    // node layer: out[j] = sigmoid(bn[j] + sum_k agg[k]*Wn[k][j]), j = lane
    float o = bn[lane];
    #pragma unroll
    for (int k = 0; k < EOUT; k++) {
        float ak = __shfl((k & 1) ? acc1 : acc0, k >> 1);
        o = fmaf(ak, Wn[k * NOUT + lane], o);
    }
    out[((size_t)b * N + node) * NOUT + lane] = sigmoidf_(o);
}

// ---------------------------------------------------------------------------
// Fallback (small ws): atomic path
// ---------------------------------------------------------------------------
__global__ void __launch_bounds__(256) edge_kernel_atomic(
    const float* __restrict__ x, const int* __restrict__ eidx,
    const float* __restrict__ ea,
    const float* __restrict__ wind_mean, const float* __restrict__ wind_std,
    const float* __restrict__ W1, const float* __restrict__ b1,
    const float* __restrict__ W2, const float* __restrict__ b2,
    const float* __restrict__ stats, float* __restrict__ agg)
{
    int t = blockIdx.x * blockDim.x + threadIdx.x;
    if (t >= B * E) return;
    int b = t / E;
    int e = t - b * E;
    int src = eidx[e];
    int tgt = eidx[E + e];
    const float* xs = x + ((size_t)b * N + src) * D;
    const float* xt = x + ((size_t)b * N + tgt) * D;
    float f[FEAT];
    #pragma unroll
    for (int i = 0; i < D; i++) f[i] = xs[i];
    #pragma unroll
    for (int i = 0; i < D; i++) f[D + i] = xt[i];
    float2 eav = *(const float2*)(ea + 2 * (size_t)e);
    f[32] = (eav.x - stats[4]) * stats[5];
    f[33] = (eav.y - stats[6]) * stats[7];
    float speed = f[14] * wind_std[0] + wind_mean[0];
    float sdir  = f[15] * wind_std[1] + wind_mean[1];
    f[34] = fmaxf(3.0f * speed * cosf(fabsf(eav.y - sdir)) / eav.x, 0.0f);
    float h[EH];
    #pragma unroll
    for (int j = 0; j < EH; j++) h[j] = b1[j];
    #pragma unroll
    for (int k = 0; k < FEAT; k++) {
        float fk = f[k];
        #pragma unroll
        for (int j = 0; j < EH; j++) h[j] = fmaf(fk, W1[k * EH + j], h[j]);
    }
    #pragma unroll
    for (int j = 0; j < EH; j++) h[j] = sigmoidf_(h[j]);
    float o[EOUT];
    #pragma unroll
    for (int j = 0; j < EOUT; j++) o[j] = b2[j];
    #pragma unroll
    for (int k = 0; k < EH; k++) {
        float hk = h[k];
        #pragma unroll
        for (int j = 0; j < EOUT; j++) o[j] = fmaf(hk, W2[k * EOUT + j], o[j]);
    }
    float* at = agg + ((size_t)b * N + tgt) * EOUT;
    float* as = agg + ((size_t)b * N + src) * EOUT;
    #pragma unroll
    for (int j = 0; j < EOUT; j++) {
        float v = sigmoidf_(o[j]);
        atomicAdd(at + j,  v);
        atomicAdd(as + j, -v);
    }
}

__global__ void __launch_bounds__(256) node_kernel_fallback(
    const float* __restrict__ agg, const float* __restrict__ Wn,
    const float* __restrict__ bn, float* __restrict__ out)
{
    int t = blockIdx.x * blockDim.x + threadIdx.x;
    if (t >= B * N * NOUT) return;
    int row = t >> 6;
    int j   = t & 63;
    const float* a = agg + (size_t)row * EOUT;
    float acc = bn[j];
    #pragma unroll
    for (int k = 0; k < EOUT; k++) acc = fmaf(a[k], Wn[k * NOUT + j], acc);
    out[t] = sigmoidf_(acc);
}

// ---------------------------------------------------------------------------
extern "C" void kernel_launch(void* const* d_in, const int* in_sizes, int n_in,
                              void* d_out, int out_size, void* d_ws, size_t ws_size,
                              hipStream_t stream) {
    const float* x         = (const float*)d_in[0];
    const int*   eidx      = (const int*)d_in[1];
    const float* ea        = (const float*)d_in[2];
    const float* wind_mean = (const float*)d_in[3];
    const float* wind_std  = (const float*)d_in[4];
    const float* W1        = (const float*)d_in[5];
    const float* b1        = (const float*)d_in[6];
    const float* W2        = (const float*)d_in[7];
    const float* b2        = (const float*)d_in[8];
    const float* Wn        = (const float*)d_in[9];
    const float* bn        = (const float*)d_in[10];
    float* out = (float*)d_out;

    char* ws = (char*)d_ws;
    // layout:
    //   stats [0,256) | offs [256,80384) | cnt/cursor [80384,160512)
    //   lists [160512,2720512)
    //   P [2720512,12960512) | Q [12960512,23200512) | eBuf [23200512,...)
    float*          stats = (float*)(ws + 0);
    int*            offs  = (int*)(ws + 256);
    int*            cnt   = (int*)(ws + 80384);
    int*            lists = (int*)(ws + 160512);
    float*          P     = (float*)(ws + 2720512);
    float*          Q     = (float*)(ws + 12960512);
    unsigned short* eBuf  = (unsigned short*)(ws + 23200512);
    const size_t fixed = 23200512;
    const size_t perBatch = (size_t)E * EH * sizeof(unsigned short); // 20,480,000

    if (ws_size >= fixed + perBatch) {
        int chunk = (int)((ws_size - fixed) / perBatch);
        if (chunk > 4) chunk = 4;   // eBuf chunk 82 MB -> L3-resident

        hipMemsetAsync(ws, 0, 160512, stream);

        stats_kernel<<<256, 256, 0, stream>>>(ea, stats);
        finalize_kernel<<<1, 64, 0, stream>>>(stats);
        count_kernel<<<(E + 255) / 256, 256, 0, stream>>>(eidx, cnt);
        scan_kernel<<<1, 1024, 0, stream>>>(cnt, offs, cnt);
        fill_kernel<<<(E + 255) / 256, 256, 0, stream>>>(eidx, cnt, lists);
        pq_kernel<<<(B * N * 64) / 256, 256, 0, stream>>>(x, W1, b1, P, Q);

        for (int b0 = 0; b0 < B; b0 += chunk) {
            int nb = B - b0; if (nb > chunk) nb = chunk;
            int nwork = nb * E;
            edge_mlp_kernel<<<(nwork + 255) / 256, 256, 0, stream>>>(
                x, eidx, ea, wind_mean, wind_std, W1, W2, b2, stats,
                P, Q, eBuf, b0, nb);
            gather_kernel<<<nb * (N * 64 / 256), 256, 0, stream>>>(
                eBuf, offs, lists, Wn, bn, out, b0, nb);
        }
    } else {
        float* agg = (float*)(ws + 256);
        size_t zero_bytes = 256 + (size_t)B * N * EOUT * sizeof(float);
        hipMemsetAsync(ws, 0, zero_bytes, stream);
        stats_kernel<<<256, 256, 0, stream>>>(ea, stats);
        finalize_kernel<<<1, 64, 0, stream>>>(stats);
        int nwork = B * E;
        edge_kernel_atomic<<<(nwork + 255) / 256, 256, 0, stream>>>(
            x, eidx, ea, wind_mean, wind_std, W1, b1, W2, b2, stats, agg);
        int nout_elems = B * N * NOUT;
        node_kernel_fallback<<<(nout_elems + 255) / 256, 256, 0, stream>>>(
            agg, Wn, bn, out);
    }
}

// Round 5
// 492.665 us; speedup vs baseline: 1.3431x; 1.0772x over previous
//
#include <hip/hip_runtime.h>
#include <hip/hip_bf16.h>
#include <math.h>

#define B 8
#define N 10000
#define D 16
#define E 320000
#define EH 32
#define EOUT 30
#define NOUT 64
#define FEAT 35   // 2*D + 2 + 1

// fast sigmoid: v_exp_f32 + v_rcp_f32 (no precise-division sequence)
__device__ __forceinline__ float sigmoidf_(float v) {
    return __builtin_amdgcn_rcpf(1.0f + __expf(-v));
}

__device__ __forceinline__ unsigned int pack_bf16_2(float a, float b) {
    unsigned ua = __float_as_uint(a), ub = __float_as_uint(b);
    ua = (ua + 0x7FFFu + ((ua >> 16) & 1u)) >> 16;
    ub = (ub + 0x7FFFu + ((ub >> 16) & 1u)) >> 16;
    return ua | (ub << 16);
}

// ---------------------------------------------------------------------------
// Fused: edge_attr column stats (mean/std ddof=1) + CSR degree counting
// ---------------------------------------------------------------------------
__global__ void stats_count_kernel(const float* __restrict__ ea,
                                   const int* __restrict__ eidx,
                                   float* __restrict__ stats,
                                   int* __restrict__ cnt) {
    float s0 = 0.f, s1 = 0.f, q0 = 0.f, q1 = 0.f;
    for (int i = blockIdx.x * blockDim.x + threadIdx.x; i < E; i += gridDim.x * blockDim.x) {
        float2 v = *(const float2*)(ea + 2 * (size_t)i);
        s0 += v.x; q0 += v.x * v.x;
        s1 += v.y; q1 += v.y * v.y;
        atomicAdd(&cnt[eidx[E + i]], 1);      // tgt (in)
        atomicAdd(&cnt[N + eidx[i]], 1);      // src (out)
    }
    #pragma unroll
    for (int off = 32; off > 0; off >>= 1) {
        s0 += __shfl_down(s0, off);
        s1 += __shfl_down(s1, off);
        q0 += __shfl_down(q0, off);
        q1 += __shfl_down(q1, off);
    }
    if ((threadIdx.x & 63) == 0) {
        atomicAdd(&stats[0], s0);
        atomicAdd(&stats[1], s1);
        atomicAdd(&stats[2], q0);
        atomicAdd(&stats[3], q1);
    }
}

// ---------------------------------------------------------------------------
// Scan (single block) + stats finalize on thread 0
// ---------------------------------------------------------------------------
__global__ void __launch_bounds__(1024) scan_kernel(const int* __restrict__ cnt_in,
                                                    int* __restrict__ offs,
                                                    int* __restrict__ cursor,
                                                    float* __restrict__ stats) {
    if (threadIdx.x == 0) {
        const float n = (float)E;
        float s0 = stats[0], s1 = stats[1], q0 = stats[2], q1 = stats[3];
        float v0 = (q0 - s0 * s0 / n) / (n - 1.0f);
        float v1 = (q1 - s1 * s1 / n) / (n - 1.0f);
        stats[4] = s0 / n;
        stats[5] = 1.0f / sqrtf(v0);
        stats[6] = s1 / n;
        stats[7] = 1.0f / sqrtf(v1);
    }
    const int M = 2 * N;
    const int CH = 20;
    __shared__ int lds[1024];
    int t = threadIdx.x;
    int base = t * CH;
    int loc[CH];
    int s = 0;
    #pragma unroll
    for (int i = 0; i < CH; i++) {
        int idx = base + i;
        int v = (idx < M) ? cnt_in[idx] : 0;
        loc[i] = s;
        s += v;
    }
    lds[t] = s;
    __syncthreads();
    for (int off = 1; off < 1024; off <<= 1) {
        int v = (t >= off) ? lds[t - off] : 0;
        __syncthreads();
        lds[t] += v;
        __syncthreads();
    }
    int tbase = (t > 0) ? lds[t - 1] : 0;
    #pragma unroll
    for (int i = 0; i < CH; i++) {
        int idx = base + i;
        if (idx < M) {
            offs[idx] = tbase + loc[i];
            cursor[idx] = tbase + loc[i];
        }
    }
    if (t == 1023) offs[M] = lds[1023];
}

__global__ void fill_kernel(const int* __restrict__ eidx, int* __restrict__ cursor,
                            int* __restrict__ lists) {
    int e = blockIdx.x * blockDim.x + threadIdx.x;
    if (e >= E) return;
    int p = atomicAdd(&cursor[eidx[E + e]], 1);
    lists[p] = e;
    int q = atomicAdd(&cursor[N + eidx[e]], 1);
    lists[q] = e;
}

// ---------------------------------------------------------------------------
// P/Q precompute: P[b,n,:] = x[b,n]@W1[0:16,:], Q[b,n,:] = x[b,n]@W1[16:32,:]+b1
// ---------------------------------------------------------------------------
__global__ void __launch_bounds__(256) pq_kernel(
    const float* __restrict__ x, const float* __restrict__ W1,
    const float* __restrict__ b1, float* __restrict__ P, float* __restrict__ Q)
{
    int wid = (blockIdx.x * blockDim.x + threadIdx.x) >> 6;
    int lane = threadIdx.x & 63;
    if (wid >= B * N) return;
    int j = lane & 31;
    int half = lane >> 5;
    const float* xr = x + (size_t)wid * D;
    float acc = half ? b1[j] : 0.f;
    const float* Wb = W1 + (half ? D * EH : 0);
    #pragma unroll
    for (int d = 0; d < D; d++)
        acc = fmaf(xr[d], Wb[d * EH + j], acc);
    float* dst = half ? Q : P;
    dst[(size_t)wid * EH + j] = acc;
}

// ---------------------------------------------------------------------------
// Edge MLP (factored layer 1); stores ONE bf16 row (64B) per edge, edge order
// ---------------------------------------------------------------------------
__global__ void __launch_bounds__(256) edge_mlp_kernel(
    const float* __restrict__ x, const int* __restrict__ eidx,
    const float* __restrict__ ea,
    const float* __restrict__ wind_mean, const float* __restrict__ wind_std,
    const float* __restrict__ W1, const float* __restrict__ W2,
    const float* __restrict__ b2, const float* __restrict__ stats,
    const float* __restrict__ P, const float* __restrict__ Q,
    unsigned short* __restrict__ eBuf, int b0, int nb)
{
    int t = blockIdx.x * blockDim.x + threadIdx.x;
    if (t >= nb * E) return;
    int bb = t / E;
    int e = t - bb * E;
    int b = b0 + bb;

    int src = eidx[e];
    int tgt = eidx[E + e];

    const float4* Pr = (const float4*)(P + ((size_t)b * N + src) * EH);
    const float4* Qr = (const float4*)(Q + ((size_t)b * N + tgt) * EH);

    float h[EH];
    #pragma unroll
    for (int i = 0; i < 8; i++) {
        float4 p = Pr[i];
        float4 q = Qr[i];
        h[4 * i + 0] = p.x + q.x;
        h[4 * i + 1] = p.y + q.y;
        h[4 * i + 2] = p.z + q.z;
        h[4 * i + 3] = p.w + q.w;
    }

    float2 eav = *(const float2*)(ea + 2 * (size_t)e);
    float dist = eav.x, cdir = eav.y;
    float f32v = (dist - stats[4]) * stats[5];
    float f33v = (cdir - stats[6]) * stats[7];

    float2 xw = *(const float2*)(x + ((size_t)b * N + src) * D + 14);
    float speed = xw.x * wind_std[0] + wind_mean[0];
    float sdir  = xw.y * wind_std[1] + wind_mean[1];
    float ew = fmaxf(3.0f * speed * cosf(fabsf(cdir - sdir)) *
                     __builtin_amdgcn_rcpf(dist), 0.0f);

    const float* W1r32 = W1 + 32 * EH;
    const float* W1r33 = W1 + 33 * EH;
    const float* W1r34 = W1 + 34 * EH;
    #pragma unroll
    for (int j = 0; j < EH; j++) {
        float v = h[j];
        v = fmaf(f32v, W1r32[j], v);
        v = fmaf(f33v, W1r33[j], v);
        v = fmaf(ew,   W1r34[j], v);
        h[j] = sigmoidf_(v);
    }

    float o[EOUT];
    #pragma unroll
    for (int j = 0; j < EOUT; j++) o[j] = b2[j];
    #pragma unroll
    for (int k = 0; k < EH; k++) {
        float hk = h[k];
        #pragma unroll
        for (int j = 0; j < EOUT; j++)
            o[j] = fmaf(hk, W2[k * EOUT + j], o[j]);
    }

    uint4 u[4];
    unsigned* uu = (unsigned*)u;
    #pragma unroll
    for (int i = 0; i < 15; i++) {
        float a = sigmoidf_(o[2 * i]);
        float c = sigmoidf_(o[2 * i + 1]);
        uu[i] = pack_bf16_2(a, c);
    }
    uu[15] = 0u;

    uint4* row = (uint4*)(eBuf + ((size_t)bb * E + e) * EH);
    #pragma unroll
    for (int i = 0; i < 4; i++) row[i] = u[i];
}

// ---------------------------------------------------------------------------
// Gather + node MLP. One wave per (bb,node). Packed: each lane loads a uint
// (2 bf16 cols); 16 lanes/row -> 4 rows per wave iteration (256 B/instr).
// ---------------------------------------------------------------------------
__global__ void __launch_bounds__(256) gather_kernel(
    const unsigned short* __restrict__ eBuf, const int* __restrict__ offs,
    const int* __restrict__ lists, const float* __restrict__ Wn,
    const float* __restrict__ bn, float* __restrict__ out, int b0, int nb)
{
    int wid = (blockIdx.x * blockDim.x + threadIdx.x) >> 6;
    int lane = threadIdx.x & 63;
    if (wid >= nb * N) return;
    int bb = wid / N;
    int node = wid - bb * N;
    int b = b0 + bb;

    int q  = lane >> 4;      // quarter 0..3 -> which row of the group of 4
    int c2 = lane & 15;      // uint index: covers cols 2*c2, 2*c2+1
    const unsigned* ebase = (const unsigned*)(eBuf + (size_t)bb * E * EH);

    float acc0 = 0.f, acc1 = 0.f;

    {
        int s = offs[node], e1 = offs[node + 1];
        for (int base = s; base < e1; base += 64) {
            int n = e1 - base; if (n > 64) n = 64;
            int myeid = (lane < n) ? lists[base + lane] : 0;
            for (int i = 0; i < n; i += 4) {
                int sel = i + q;
                int eid = __shfl(myeid, sel);
                if (sel < n) {
                    unsigned v = ebase[(size_t)eid * 16 + c2];
                    acc0 += __uint_as_float(v << 16);
                    acc1 += __uint_as_float(v & 0xFFFF0000u);
                }
            }
        }
    }
    {
        int s = offs[N + node], e1 = offs[N + node + 1];
        for (int base = s; base < e1; base += 64) {
            int n = e1 - base; if (n > 64) n = 64;
            int myeid = (lane < n) ? lists[base + lane] : 0;
            for (int i = 0; i < n; i += 4) {
                int sel = i + q;
                int eid = __shfl(myeid, sel);
                if (sel < n) {
                    unsigned v = ebase[(size_t)eid * 16 + c2];
                    acc0 -= __uint_as_float(v << 16);
                    acc1 -= __uint_as_float(v & 0xFFFF0000u);
                }
            }
        }
    }

    acc0 += __shfl_xor(acc0, 16); acc1 += __shfl_xor(acc1, 16);
    acc0 += __shfl_xor(acc0, 32); acc1 += __shfl_xor(acc1, 32);

    float o = bn[lane];
    #pragma unroll
    for (int k = 0; k < EOUT; k++) {
        float ak = __shfl((k & 1) ? acc1 : acc0, k >> 1);
        o = fmaf(ak, Wn[k * NOUT + lane], o);
    }
    out[((size_t)b * N + node) * NOUT + lane] = sigmoidf_(o);
}

// ---------------------------------------------------------------------------
// Fallback (small ws): atomic path
// ---------------------------------------------------------------------------
__global__ void __launch_bounds__(256) edge_kernel_atomic(
    const float* __restrict__ x, const int* __restrict__ eidx,
    const float* __restrict__ ea,
    const float* __restrict__ wind_mean, const float* __restrict__ wind_std,
    const float* __restrict__ W1, const float* __restrict__ b1,
    const float* __restrict__ W2, const float* __restrict__ b2,
    const float* __restrict__ stats, float* __restrict__ agg)
{
    int t = blockIdx.x * blockDim.x + threadIdx.x;
    if (t >= B * E) return;
    int b = t / E;
    int e = t - b * E;
    int src = eidx[e];
    int tgt = eidx[E + e];
    const float* xs = x + ((size_t)b * N + src) * D;
    const float* xt = x + ((size_t)b * N + tgt) * D;
    float f[FEAT];
    #pragma unroll
    for (int i = 0; i < D; i++) f[i] = xs[i];
    #pragma unroll
    for (int i = 0; i < D; i++) f[D + i] = xt[i];
    float2 eav = *(const float2*)(ea + 2 * (size_t)e);
    f[32] = (eav.x - stats[4]) * stats[5];
    f[33] = (eav.y - stats[6]) * stats[7];
    float speed = f[14] * wind_std[0] + wind_mean[0];
    float sdir  = f[15] * wind_std[1] + wind_mean[1];
    f[34] = fmaxf(3.0f * speed * cosf(fabsf(eav.y - sdir)) / eav.x, 0.0f);
    float h[EH];
    #pragma unroll
    for (int j = 0; j < EH; j++) h[j] = b1[j];
    #pragma unroll
    for (int k = 0; k < FEAT; k++) {
        float fk = f[k];
        #pragma unroll
        for (int j = 0; j < EH; j++) h[j] = fmaf(fk, W1[k * EH + j], h[j]);
    }
    #pragma unroll
    for (int j = 0; j < EH; j++) h[j] = sigmoidf_(h[j]);
    float o[EOUT];
    #pragma unroll
    for (int j = 0; j < EOUT; j++) o[j] = b2[j];
    #pragma unroll
    for (int k = 0; k < EH; k++) {
        float hk = h[k];
        #pragma unroll
        for (int j = 0; j < EOUT; j++) o[j] = fmaf(hk, W2[k * EOUT + j], o[j]);
    }
    float* at = agg + ((size_t)b * N + tgt) * EOUT;
    float* as = agg + ((size_t)b * N + src) * EOUT;
    #pragma unroll
    for (int j = 0; j < EOUT; j++) {
        float v = sigmoidf_(o[j]);
        atomicAdd(at + j,  v);
        atomicAdd(as + j, -v);
    }
}

__global__ void __launch_bounds__(256) node_kernel_fallback(
    const float* __restrict__ agg, const float* __restrict__ Wn,
    const float* __restrict__ bn, float* __restrict__ out)
{
    int t = blockIdx.x * blockDim.x + threadIdx.x;
    if (t >= B * N * NOUT) return;
    int row = t >> 6;
    int j   = t & 63;
    const float* a = agg + (size_t)row * EOUT;
    float acc = bn[j];
    #pragma unroll
    for (int k = 0; k < EOUT; k++) acc = fmaf(a[k], Wn[k * NOUT + j], acc);
    out[t] = sigmoidf_(acc);
}

// ---------------------------------------------------------------------------
extern "C" void kernel_launch(void* const* d_in, const int* in_sizes, int n_in,
                              void* d_out, int out_size, void* d_ws, size_t ws_size,
                              hipStream_t stream) {
    const float* x         = (const float*)d_in[0];
    const int*   eidx      = (const int*)d_in[1];
    const float* ea        = (const float*)d_in[2];
    const float* wind_mean = (const float*)d_in[3];
    const float* wind_std  = (const float*)d_in[4];
    const float* W1        = (const float*)d_in[5];
    const float* b1        = (const float*)d_in[6];
    const float* W2        = (const float*)d_in[7];
    const float* b2        = (const float*)d_in[8];
    const float* Wn        = (const float*)d_in[9];
    const float* bn        = (const float*)d_in[10];
    float* out = (float*)d_out;

    char* ws = (char*)d_ws;
    // layout:
    //   stats [0,256) | offs [256,80384) | cnt/cursor [80384,160512)
    //   lists [160512,2720512)
    //   P [2720512,12960512) | Q [12960512,23200512) | eBuf [23200512,...)
    float*          stats = (float*)(ws + 0);
    int*            offs  = (int*)(ws + 256);
    int*            cnt   = (int*)(ws + 80384);
    int*            lists = (int*)(ws + 160512);
    float*          P     = (float*)(ws + 2720512);
    float*          Q     = (float*)(ws + 12960512);
    unsigned short* eBuf  = (unsigned short*)(ws + 23200512);
    const size_t fixed = 23200512;
    const size_t perBatch = (size_t)E * EH * sizeof(unsigned short); // 20,480,000

    if (ws_size >= fixed + perBatch) {
        int chunk = (int)((ws_size - fixed) / perBatch);
        if (chunk > 4) chunk = 4;   // eBuf chunk 82 MB -> L3-resident

        hipMemsetAsync(ws, 0, 160512, stream);

        stats_count_kernel<<<256, 256, 0, stream>>>(ea, eidx, stats, cnt);
        scan_kernel<<<1, 1024, 0, stream>>>(cnt, offs, cnt, stats);
        fill_kernel<<<(E + 255) / 256, 256, 0, stream>>>(eidx, cnt, lists);
        pq_kernel<<<(B * N * 64) / 256, 256, 0, stream>>>(x, W1, b1, P, Q);

        for (int b0 = 0; b0 < B; b0 += chunk) {
            int nb = B - b0; if (nb > chunk) nb = chunk;
            int nwork = nb * E;
            edge_mlp_kernel<<<(nwork + 255) / 256, 256, 0, stream>>>(
                x, eidx, ea, wind_mean, wind_std, W1, W2, b2, stats,
                P, Q, eBuf, b0, nb);
            gather_kernel<<<nb * (N * 64 / 256), 256, 0, stream>>>(
                eBuf, offs, lists, Wn, bn, out, b0, nb);
        }
    } else {
        float* agg = (float*)(ws + 256);
        size_t zero_bytes = 256 + (size_t)B * N * EOUT * sizeof(float);
        hipMemsetAsync(ws, 0, zero_bytes, stream);
        stats_count_kernel<<<256, 256, 0, stream>>>(ea, eidx, stats, cnt);
        scan_kernel<<<1, 1024, 0, stream>>>(cnt, offs, cnt, stats);
        int nwork = B * E;
        edge_kernel_atomic<<<(nwork + 255) / 256, 256, 0, stream>>>(
            x, eidx, ea, wind_mean, wind_std, W1, b1, W2, b2, stats, agg);
        int nout_elems = B * N * NOUT;
        node_kernel_fallback<<<(nout_elems + 255) / 256, 256, 0, stream>>>(
            agg, Wn, bn, out);
    }
}

// Round 6
// 463.346 us; speedup vs baseline: 1.4281x; 1.0633x over previous
//
#include <hip/hip_runtime.h>
#include <hip/hip_bf16.h>
#include <math.h>

#define B 8
#define N 10000
#define D 16
#define E 320000
#define EH 32
#define EOUT 30
#define NOUT 64
#define FEAT 35   // 2*D + 2 + 1
#define FILL_BLOCKS ((E + 255) / 256)      // 1250
#define PQ_BLOCKS   ((B * N * 64) / 256)   // 20000

// fast sigmoid: v_exp_f32 + v_rcp_f32 (no precise-division sequence)
__device__ __forceinline__ float sigmoidf_(float v) {
    return __builtin_amdgcn_rcpf(1.0f + __expf(-v));
}

__device__ __forceinline__ unsigned int pack_bf16_2(float a, float b) {
    unsigned ua = __float_as_uint(a), ub = __float_as_uint(b);
    ua = (ua + 0x7FFFu + ((ua >> 16) & 1u)) >> 16;
    ub = (ub + 0x7FFFu + ((ub >> 16) & 1u)) >> 16;
    return ua | (ub << 16);
}

// ---------------------------------------------------------------------------
// Fused: edge_attr column stats (mean/std ddof=1) + CSR degree counting
// ---------------------------------------------------------------------------
__global__ void stats_count_kernel(const float* __restrict__ ea,
                                   const int* __restrict__ eidx,
                                   float* __restrict__ stats,
                                   int* __restrict__ cnt) {
    float s0 = 0.f, s1 = 0.f, q0 = 0.f, q1 = 0.f;
    for (int i = blockIdx.x * blockDim.x + threadIdx.x; i < E; i += gridDim.x * blockDim.x) {
        float2 v = *(const float2*)(ea + 2 * (size_t)i);
        s0 += v.x; q0 += v.x * v.x;
        s1 += v.y; q1 += v.y * v.y;
        atomicAdd(&cnt[eidx[E + i]], 1);      // tgt (in)
        atomicAdd(&cnt[N + eidx[i]], 1);      // src (out)
    }
    #pragma unroll
    for (int off = 32; off > 0; off >>= 1) {
        s0 += __shfl_down(s0, off);
        s1 += __shfl_down(s1, off);
        q0 += __shfl_down(q0, off);
        q1 += __shfl_down(q1, off);
    }
    if ((threadIdx.x & 63) == 0) {
        atomicAdd(&stats[0], s0);
        atomicAdd(&stats[1], s1);
        atomicAdd(&stats[2], q0);
        atomicAdd(&stats[3], q1);
    }
}

// ---------------------------------------------------------------------------
// Scan (single block) + stats finalize on thread 0
// ---------------------------------------------------------------------------
__global__ void __launch_bounds__(1024) scan_kernel(const int* __restrict__ cnt_in,
                                                    int* __restrict__ offs,
                                                    int* __restrict__ cursor,
                                                    float* __restrict__ stats) {
    if (threadIdx.x == 0) {
        const float n = (float)E;
        float s0 = stats[0], s1 = stats[1], q0 = stats[2], q1 = stats[3];
        float v0 = (q0 - s0 * s0 / n) / (n - 1.0f);
        float v1 = (q1 - s1 * s1 / n) / (n - 1.0f);
        stats[4] = s0 / n;
        stats[5] = 1.0f / sqrtf(v0);
        stats[6] = s1 / n;
        stats[7] = 1.0f / sqrtf(v1);
    }
    const int M = 2 * N;
    const int CH = 20;
    __shared__ int lds[1024];
    int t = threadIdx.x;
    int base = t * CH;
    int loc[CH];
    int s = 0;
    #pragma unroll
    for (int i = 0; i < CH; i++) {
        int idx = base + i;
        int v = (idx < M) ? cnt_in[idx] : 0;
        loc[i] = s;
        s += v;
    }
    lds[t] = s;
    __syncthreads();
    for (int off = 1; off < 1024; off <<= 1) {
        int v = (t >= off) ? lds[t - off] : 0;
        __syncthreads();
        lds[t] += v;
        __syncthreads();
    }
    int tbase = (t > 0) ? lds[t - 1] : 0;
    #pragma unroll
    for (int i = 0; i < CH; i++) {
        int idx = base + i;
        if (idx < M) {
            offs[idx] = tbase + loc[i];
            cursor[idx] = tbase + loc[i];
        }
    }
    if (t == 1023) offs[M] = lds[1023];
}

// ---------------------------------------------------------------------------
// Fused fill (CSR lists) + P/Q precompute. Block-range split:
//   blocks [0, FILL_BLOCKS): lists fill
//   blocks [FILL_BLOCKS, FILL_BLOCKS+PQ_BLOCKS): P/Q
// P[b,n,:] = x[b,n]@W1[0:16,:], Q[b,n,:] = x[b,n]@W1[16:32,:]+b1
// ---------------------------------------------------------------------------
__global__ void __launch_bounds__(256) fill_pq_kernel(
    const int* __restrict__ eidx, int* __restrict__ cursor,
    int* __restrict__ lists,
    const float* __restrict__ x, const float* __restrict__ W1,
    const float* __restrict__ b1, float* __restrict__ P, float* __restrict__ Q)
{
    if (blockIdx.x < FILL_BLOCKS) {
        int e = blockIdx.x * 256 + threadIdx.x;
        if (e >= E) return;
        int p = atomicAdd(&cursor[eidx[E + e]], 1);
        lists[p] = e;
        int q = atomicAdd(&cursor[N + eidx[e]], 1);
        lists[q] = e;
    } else {
        int wid = ((blockIdx.x - FILL_BLOCKS) * 256 + threadIdx.x) >> 6;
        int lane = threadIdx.x & 63;
        if (wid >= B * N) return;
        int j = lane & 31;
        int half = lane >> 5;
        const float* xr = x + (size_t)wid * D;
        float acc = half ? b1[j] : 0.f;
        const float* Wb = W1 + (half ? D * EH : 0);
        #pragma unroll
        for (int d = 0; d < D; d++)
            acc = fmaf(xr[d], Wb[d * EH + j], acc);
        float* dst = half ? Q : P;
        dst[(size_t)wid * EH + j] = acc;
    }
}

// ---------------------------------------------------------------------------
// Edge MLP (factored layer 1); stores ONE bf16 row (64B) per edge, edge order
// ---------------------------------------------------------------------------
__global__ void __launch_bounds__(256) edge_mlp_kernel(
    const float* __restrict__ x, const int* __restrict__ eidx,
    const float* __restrict__ ea,
    const float* __restrict__ wind_mean, const float* __restrict__ wind_std,
    const float* __restrict__ W1, const float* __restrict__ W2,
    const float* __restrict__ b2, const float* __restrict__ stats,
    const float* __restrict__ P, const float* __restrict__ Q,
    unsigned short* __restrict__ eBuf, int b0, int nb)
{
    int t = blockIdx.x * blockDim.x + threadIdx.x;
    if (t >= nb * E) return;
    int bb = t / E;
    int e = t - bb * E;
    int b = b0 + bb;

    int src = eidx[e];
    int tgt = eidx[E + e];

    const float4* Pr = (const float4*)(P + ((size_t)b * N + src) * EH);
    const float4* Qr = (const float4*)(Q + ((size_t)b * N + tgt) * EH);

    float h[EH];
    #pragma unroll
    for (int i = 0; i < 8; i++) {
        float4 p = Pr[i];
        float4 q = Qr[i];
        h[4 * i + 0] = p.x + q.x;
        h[4 * i + 1] = p.y + q.y;
        h[4 * i + 2] = p.z + q.z;
        h[4 * i + 3] = p.w + q.w;
    }

    float2 eav = *(const float2*)(ea + 2 * (size_t)e);
    float dist = eav.x, cdir = eav.y;
    float f32v = (dist - stats[4]) * stats[5];
    float f33v = (cdir - stats[6]) * stats[7];

    float2 xw = *(const float2*)(x + ((size_t)b * N + src) * D + 14);
    float speed = xw.x * wind_std[0] + wind_mean[0];
    float sdir  = xw.y * wind_std[1] + wind_mean[1];
    float ew = fmaxf(3.0f * speed * cosf(fabsf(cdir - sdir)) *
                     __builtin_amdgcn_rcpf(dist), 0.0f);

    const float* W1r32 = W1 + 32 * EH;
    const float* W1r33 = W1 + 33 * EH;
    const float* W1r34 = W1 + 34 * EH;
    #pragma unroll
    for (int j = 0; j < EH; j++) {
        float v = h[j];
        v = fmaf(f32v, W1r32[j], v);
        v = fmaf(f33v, W1r33[j], v);
        v = fmaf(ew,   W1r34[j], v);
        h[j] = sigmoidf_(v);
    }

    float o[EOUT];
    #pragma unroll
    for (int j = 0; j < EOUT; j++) o[j] = b2[j];
    #pragma unroll
    for (int k = 0; k < EH; k++) {
        float hk = h[k];
        #pragma unroll
        for (int j = 0; j < EOUT; j++)
            o[j] = fmaf(hk, W2[k * EOUT + j], o[j]);
    }

    uint4 u[4];
    unsigned* uu = (unsigned*)u;
    #pragma unroll
    for (int i = 0; i < 15; i++) {
        float a = sigmoidf_(o[2 * i]);
        float c = sigmoidf_(o[2 * i + 1]);
        uu[i] = pack_bf16_2(a, c);
    }
    uu[15] = 0u;

    uint4* row = (uint4*)(eBuf + ((size_t)bb * E + e) * EH);
    #pragma unroll
    for (int i = 0; i < 4; i++) row[i] = u[i];
}

// ---------------------------------------------------------------------------
// Gather + node MLP. One wave per (bb,node).
// Lane loads uint2 (4 bf16 cols); 8 lanes/row -> 8 rows per iteration
// (512 B per wave instr). Edge ids come from a coalesced lists[] load
// (8 distinct addresses/wave) -- no bpermute in the inner loop.
// ---------------------------------------------------------------------------
__global__ void __launch_bounds__(256) gather_kernel(
    const unsigned short* __restrict__ eBuf, const int* __restrict__ offs,
    const int* __restrict__ lists, const float* __restrict__ Wn,
    const float* __restrict__ bn, float* __restrict__ out, int b0, int nb)
{
    int wid = (blockIdx.x * blockDim.x + threadIdx.x) >> 6;
    int lane = threadIdx.x & 63;
    if (wid >= nb * N) return;
    int bb = wid / N;
    int node = wid - bb * N;
    int b = b0 + bb;

    int g = lane >> 3;       // row-group 0..7
    int c = lane & 7;        // uint2 index in row: covers cols 4c..4c+3
    const uint2* ebase = (const uint2*)(eBuf + (size_t)bb * E * EH); // 8 uint2/row

    float a0 = 0.f, a1 = 0.f, a2 = 0.f, a3 = 0.f;

    // in-list: add
    {
        int s = offs[node], e1 = offs[node + 1];
        for (int r = s; r < e1; r += 8) {
            int row = r + g;
            if (row < e1) {
                int eid = lists[row];
                uint2 v = ebase[(size_t)eid * 8 + c];
                a0 += __uint_as_float(v.x << 16);
                a1 += __uint_as_float(v.x & 0xFFFF0000u);
                a2 += __uint_as_float(v.y << 16);
                a3 += __uint_as_float(v.y & 0xFFFF0000u);
            }
        }
    }
    // out-list: subtract
    {
        int s = offs[N + node], e1 = offs[N + node + 1];
        for (int r = s; r < e1; r += 8) {
            int row = r + g;
            if (row < e1) {
                int eid = lists[row];
                uint2 v = ebase[(size_t)eid * 8 + c];
                a0 -= __uint_as_float(v.x << 16);
                a1 -= __uint_as_float(v.x & 0xFFFF0000u);
                a2 -= __uint_as_float(v.y << 16);
                a3 -= __uint_as_float(v.y & 0xFFFF0000u);
            }
        }
    }

    // fold the 8 row-groups: lanes sharing (lane&7) end with full column sums
    a0 += __shfl_xor(a0, 8);  a1 += __shfl_xor(a1, 8);
    a2 += __shfl_xor(a2, 8);  a3 += __shfl_xor(a3, 8);
    a0 += __shfl_xor(a0, 16); a1 += __shfl_xor(a1, 16);
    a2 += __shfl_xor(a2, 16); a3 += __shfl_xor(a3, 16);
    a0 += __shfl_xor(a0, 32); a1 += __shfl_xor(a1, 32);
    a2 += __shfl_xor(a2, 32); a3 += __shfl_xor(a3, 32);

    // node layer: agg[k] lives in a{k&3} of lane (k>>2)
    float o = bn[lane];
    #pragma unroll
    for (int k = 0; k < EOUT; k++) {
        float av;
        switch (k & 3) {
            case 0:  av = a0; break;
            case 1:  av = a1; break;
            case 2:  av = a2; break;
            default: av = a3; break;
        }
        float ak = __shfl(av, k >> 2);
        o = fmaf(ak, Wn[k * NOUT + lane], o);
    }
    out[((size_t)b * N + node) * NOUT + lane] = sigmoidf_(o);
}

// ---------------------------------------------------------------------------
// Fallback (small ws): atomic path
// ---------------------------------------------------------------------------
__global__ void __launch_bounds__(256) edge_kernel_atomic(
    const float* __restrict__ x, const int* __restrict__ eidx,
    const float* __restrict__ ea,
    const float* __restrict__ wind_mean, const float* __restrict__ wind_std,
    const float* __restrict__ W1, const float* __restrict__ b1,
    const float* __restrict__ W2, const float* __restrict__ b2,
    const float* __restrict__ stats, float* __restrict__ agg)
{
    int t = blockIdx.x * blockDim.x + threadIdx.x;
    if (t >= B * E) return;
    int b = t / E;
    int e = t - b * E;
    int src = eidx[e];
    int tgt = eidx[E + e];
    const float* xs = x + ((size_t)b * N + src) * D;
    const float* xt = x + ((size_t)b * N + tgt) * D;
    float f[FEAT];
    #pragma unroll
    for (int i = 0; i < D; i++) f[i] = xs[i];
    #pragma unroll
    for (int i = 0; i < D; i++) f[D + i] = xt[i];
    float2 eav = *(const float2*)(ea + 2 * (size_t)e);
    f[32] = (eav.x - stats[4]) * stats[5];
    f[33] = (eav.y - stats[6]) * stats[7];
    float speed = f[14] * wind_std[0] + wind_mean[0];
    float sdir  = f[15] * wind_std[1] + wind_mean[1];
    f[34] = fmaxf(3.0f * speed * cosf(fabsf(eav.y - sdir)) / eav.x, 0.0f);
    float h[EH];
    #pragma unroll
    for (int j = 0; j < EH; j++) h[j] = b1[j];
    #pragma unroll
    for (int k = 0; k < FEAT; k++) {
        float fk = f[k];
        #pragma unroll
        for (int j = 0; j < EH; j++) h[j] = fmaf(fk, W1[k * EH + j], h[j]);
    }
    #pragma unroll
    for (int j = 0; j < EH; j++) h[j] = sigmoidf_(h[j]);
    float o[EOUT];
    #pragma unroll
    for (int j = 0; j < EOUT; j++) o[j] = b2[j];
    #pragma unroll
    for (int k = 0; k < EH; k++) {
        float hk = h[k];
        #pragma unroll
        for (int j = 0; j < EOUT; j++) o[j] = fmaf(hk, W2[k * EOUT + j], o[j]);
    }
    float* at = agg + ((size_t)b * N + tgt) * EOUT;
    float* as = agg + ((size_t)b * N + src) * EOUT;
    #pragma unroll
    for (int j = 0; j < EOUT; j++) {
        float v = sigmoidf_(o[j]);
        atomicAdd(at + j,  v);
        atomicAdd(as + j, -v);
    }
}

__global__ void __launch_bounds__(256) node_kernel_fallback(
    const float* __restrict__ agg, const float* __restrict__ Wn,
    const float* __restrict__ bn, float* __restrict__ out)
{
    int t = blockIdx.x * blockDim.x + threadIdx.x;
    if (t >= B * N * NOUT) return;
    int row = t >> 6;
    int j   = t & 63;
    const float* a = agg + (size_t)row * EOUT;
    float acc = bn[j];
    #pragma unroll
    for (int k = 0; k < EOUT; k++) acc = fmaf(a[k], Wn[k * NOUT + j], acc);
    out[t] = sigmoidf_(acc);
}

// ---------------------------------------------------------------------------
extern "C" void kernel_launch(void* const* d_in, const int* in_sizes, int n_in,
                              void* d_out, int out_size, void* d_ws, size_t ws_size,
                              hipStream_t stream) {
    const float* x         = (const float*)d_in[0];
    const int*   eidx      = (const int*)d_in[1];
    const float* ea        = (const float*)d_in[2];
    const float* wind_mean = (const float*)d_in[3];
    const float* wind_std  = (const float*)d_in[4];
    const float* W1        = (const float*)d_in[5];
    const float* b1        = (const float*)d_in[6];
    const float* W2        = (const float*)d_in[7];
    const float* b2        = (const float*)d_in[8];
    const float* Wn        = (const float*)d_in[9];
    const float* bn        = (const float*)d_in[10];
    float* out = (float*)d_out;

    char* ws = (char*)d_ws;
    // layout:
    //   stats [0,256) | offs [256,80384) | cnt/cursor [80384,160512)
    //   lists [160512,2720512)
    //   P [2720512,12960512) | Q [12960512,23200512) | eBuf [23200512,...)
    float*          stats = (float*)(ws + 0);
    int*            offs  = (int*)(ws + 256);
    int*            cnt   = (int*)(ws + 80384);
    int*            lists = (int*)(ws + 160512);
    float*          P     = (float*)(ws + 2720512);
    float*          Q     = (float*)(ws + 12960512);
    unsigned short* eBuf  = (unsigned short*)(ws + 23200512);
    const size_t fixed = 23200512;
    const size_t perBatch = (size_t)E * EH * sizeof(unsigned short); // 20,480,000

    if (ws_size >= fixed + perBatch) {
        int chunk = (int)((ws_size - fixed) / perBatch);
        if (chunk > 8) chunk = 8;   // eBuf up to 164 MB -> still L3-resident

        hipMemsetAsync(ws, 0, 160512, stream);

        stats_count_kernel<<<256, 256, 0, stream>>>(ea, eidx, stats, cnt);
        scan_kernel<<<1, 1024, 0, stream>>>(cnt, offs, cnt, stats);
        fill_pq_kernel<<<FILL_BLOCKS + PQ_BLOCKS, 256, 0, stream>>>(
            eidx, cnt, lists, x, W1, b1, P, Q);

        for (int b0 = 0; b0 < B; b0 += chunk) {
            int nb = B - b0; if (nb > chunk) nb = chunk;
            int nwork = nb * E;
            edge_mlp_kernel<<<(nwork + 255) / 256, 256, 0, stream>>>(
                x, eidx, ea, wind_mean, wind_std, W1, W2, b2, stats,
                P, Q, eBuf, b0, nb);
            gather_kernel<<<nb * (N * 64 / 256), 256, 0, stream>>>(
                eBuf, offs, lists, Wn, bn, out, b0, nb);
        }
    } else {
        float* agg = (float*)(ws + 256);
        size_t zero_bytes = 256 + (size_t)B * N * EOUT * sizeof(float);
        hipMemsetAsync(ws, 0, zero_bytes, stream);
        stats_count_kernel<<<256, 256, 0, stream>>>(ea, eidx, stats, cnt);
        scan_kernel<<<1, 1024, 0, stream>>>(cnt, offs, cnt, stats);
        int nwork = B * E;
        edge_kernel_atomic<<<(nwork + 255) / 256, 256, 0, stream>>>(
            x, eidx, ea, wind_mean, wind_std, W1, b1, W2, b2, stats, agg);
        int nout_elems = B * N * NOUT;
        node_kernel_fallback<<<(nout_elems + 255) / 256, 256, 0, stream>>>(
            agg, Wn, bn, out);
    }
}